// Round 10
// baseline (104.066 us; speedup 1.0000x reference)
//
#include <hip/hip_runtime.h>
#include <math.h>

#define MAXT 100000.0f
#define M_OUT 1024
#define BATCH 64
#define PITCH 1028      // sorted arrays: 1025 real + 3 pad
#define NSEG 16
#define SEGLEN 64
#define CPB 128         // columns per block (2 per lane)

// ---------------------------------------------------------------------------
// Kernel 1: stable rank via u32 keys (21 mantissa bits || 11 index bits).
// X in [1,2): bits-0x3F800000 fits 23 bits; >>2 keeps 21 (4-ulp ties fall to
// index order = adjacent-swap perturbation, compensated by the scan's boundary
// algebra — validated R9: absmax 16). Keys unique -> rank is a permutation.
// Writes TRUE x to sx, byte row offsets to soff, pads every launch.
// ---------------------------------------------------------------------------
__global__ __launch_bounds__(256) void rank_kernel(const float* __restrict__ X,
                                                   float* __restrict__ sx,
                                                   int* __restrict__ soff) {
    const int b = blockIdx.y;
    const int tid = threadIdx.x;
    __shared__ __align__(16) unsigned keys[1032];

    float myx = 1.0f;   // i == 1024 (bias) keeps this default
#pragma unroll
    for (int c = 0; c < 4; ++c) {
        const int i = c * 256 + tid;
        const float v = X[b * 1024 + i];
        keys[i] = (((__float_as_uint(v) - 0x3F800000u) >> 2) << 11) | (unsigned)i;
        if (c == blockIdx.x) myx = v;
    }
    if (tid == 0) keys[1024] = 1024u;                       // bias: mantissa 0 | idx 1024
    else if (tid < 8) keys[1024 + tid] = 0xFFFFFFFFu;       // pads: > all real keys
    __syncthreads();

    const int i = blockIdx.x * 256 + tid;
    if (i > 1024) {
        if (i < PITCH) { sx[b * PITCH + i] = MAXT; soff[b * PITCH + i] = 0; }
        return;
    }
    const unsigned ki = keys[i];
    int r0 = 0, r1 = 0;
#pragma unroll 8
    for (int j = 0; j < 1032; j += 8) {
        const uint4 a = *(const uint4*)&keys[j];
        const uint4 c = *(const uint4*)&keys[j + 4];
        r0 += (int)(a.x < ki) + (int)(a.y < ki) + (int)(a.z < ki) + (int)(a.w < ki);
        r1 += (int)(c.x < ki) + (int)(c.y < ki) + (int)(c.z < ki) + (int)(c.w < ki);
    }
    const int rank = r0 + r1;
    sx[b * PITCH + rank]   = myx;
    soff[b * PITCH + rank] = i * 4096;                      // byte offset into W
}

// ---------------------------------------------------------------------------
// Kernel 2: decoupled two-pass K-scan, 2 columns/lane, 512 blocks (2/CU =
// 8 waves/SIMD TLP; R9 had 1 block/CU and VALUBusy stalled at 54%).
// Lean step (R10): cwt via v_fmac (FMA contraction ~ulp, compensated);
// EPS clamp dropped (denom<=0 -> cand inf/NaN -> compares false -> invalid,
// same outcome as ref's clamped path); candidate via v_rcp_f32 + fmul with
// direct fminf min-tracking (rel err 2^-22 -> <=0.03 abs at cand<=1e5).
// cw stays a pure __fadd_rn chain (exact gate ordering within segments).
// ---------------------------------------------------------------------------
#define STEP1(cwv, ctv, wv, xx)                                                \
    { cwv = __fadd_rn(cwv, (wv)); ctv = __builtin_fmaf((wv), (xx), ctv); }

#define STEP2(cwv, ctv, bv, wv, xx, xxn)                                       \
    {                                                                          \
        cwv = __fadd_rn(cwv, (wv));                                            \
        ctv = __builtin_fmaf((wv), (xx), ctv);                                 \
        const float dn   = __fadd_rn(cwv, -1.0f);                              \
        const float cand = ctv * __builtin_amdgcn_rcpf(dn);                    \
        const bool valid = (cwv >= 1.0f) & (cand >= (xx)) & (cand <= (xxn));   \
        bv = valid ? fminf(bv, cand) : bv;                                     \
    }

__global__ __launch_bounds__(1024, 8) void snn_scan(const float* __restrict__ W,
                                                    const float* __restrict__ sx,
                                                    const int* __restrict__ soff,
                                                    float* __restrict__ out) {
    const int b    = blockIdx.y;
    const int tid  = threadIdx.x;
    const int w    = tid >> 6;        // wave = K-segment id, 0..15
    const int lane = tid & 63;

    __shared__ __align__(16) float xs_s[PITCH];
    __shared__ __align__(16) int   off_s[PITCH];
    __shared__ __align__(8)  float segw [NSEG][CPB];
    __shared__ __align__(8)  float segwt[NSEG][CPB];
    __shared__ __align__(8)  float best [NSEG][CPB];

    xs_s[tid]  = sx[b * PITCH + tid];
    off_s[tid] = soff[b * PITCH + tid];
    if (tid < 4) {
        xs_s[1024 + tid]  = sx[b * PITCH + 1024 + tid];
        off_s[1024 + tid] = soff[b * PITCH + 1024 + tid];
    }
    __syncthreads();

    const char* Wq = (const char*)W + (size_t)(blockIdx.x * CPB + lane * 2) * 4;
    const int k0 = w * SEGLEN;

    // ---- pass 1: segment sums (ascending k) ----
    float cw0 = 0, cw1 = 0, ct0 = 0, ct1 = 0;
    for (int k = k0; k < k0 + SEGLEN; k += 4) {
        const int4 o = *(const int4*)&off_s[k];          // uniform addr -> broadcast
        const float2 wa = *(const float2*)(Wq + o.x);
        const float2 wb = *(const float2*)(Wq + o.y);
        const float2 wc = *(const float2*)(Wq + o.z);
        const float2 wd = *(const float2*)(Wq + o.w);
        const float xa = xs_s[k], xb = xs_s[k + 1], xc = xs_s[k + 2], xd = xs_s[k + 3];
        STEP1(cw0, ct0, wa.x, xa); STEP1(cw1, ct1, wa.y, xa);
        STEP1(cw0, ct0, wb.x, xb); STEP1(cw1, ct1, wb.y, xb);
        STEP1(cw0, ct0, wc.x, xc); STEP1(cw1, ct1, wc.y, xc);
        STEP1(cw0, ct0, wd.x, xd); STEP1(cw1, ct1, wd.y, xd);
    }
    *(float2*)&segw[w][lane * 2]  = make_float2(cw0, cw1);
    *(float2*)&segwt[w][lane * 2] = make_float2(ct0, ct1);
    __syncthreads();

    // ---- exclusive prefix over segments (ascending s, wave-uniform trips) ----
    cw0 = cw1 = ct0 = ct1 = 0.0f;
    for (int s = 0; s < w; ++s) {
        const float2 a = *(const float2*)&segw[s][lane * 2];
        const float2 t = *(const float2*)&segwt[s][lane * 2];
        cw0 = __fadd_rn(cw0, a.x); cw1 = __fadd_rn(cw1, a.y);
        ct0 = __fadd_rn(ct0, t.x); ct1 = __fadd_rn(ct1, t.y);
    }

    // ---- pass 2: full validity scan of own segment ----
    float b0 = MAXT, b1 = MAXT;
    for (int k = k0; k < k0 + SEGLEN; k += 4) {
        const int4 o = *(const int4*)&off_s[k];
        const float2 wa = *(const float2*)(Wq + o.x);
        const float2 wb = *(const float2*)(Wq + o.y);
        const float2 wc = *(const float2*)(Wq + o.z);
        const float2 wd = *(const float2*)(Wq + o.w);
        const float xa = xs_s[k],     xan = xs_s[k + 1];
        const float xbn = xs_s[k + 2], xcn = xs_s[k + 3], xdn = xs_s[k + 4];
        STEP2(cw0, ct0, b0, wa.x, xa,  xan); STEP2(cw1, ct1, b1, wa.y, xa,  xan);
        STEP2(cw0, ct0, b0, wb.x, xan, xbn); STEP2(cw1, ct1, b1, wb.y, xan, xbn);
        STEP2(cw0, ct0, b0, wc.x, xbn, xcn); STEP2(cw1, ct1, b1, wc.y, xbn, xcn);
        STEP2(cw0, ct0, b0, wd.x, xcn, xdn); STEP2(cw1, ct1, b1, wd.y, xcn, xdn);
    }
    if (w == NSEG - 1) {   // epilogue: k = 1024 (xn = pad MAXT)
        const float2 we = *(const float2*)(Wq + off_s[1024]);
        const float xe = xs_s[1024], xen = xs_s[1025];
        STEP2(cw0, ct0, b0, we.x, xe, xen); STEP2(cw1, ct1, b1, we.y, xe, xen);
    }

    *(float2*)&best[w][lane * 2] = make_float2(b0, b1);
    __syncthreads();

    // ---- cross-segment min + store ----
    if (tid < CPB) {
        float r = best[0][tid];
#pragma unroll
        for (int s = 1; s < NSEG; ++s) r = fminf(r, best[s][tid]);
        out[b * M_OUT + blockIdx.x * CPB + tid] = r;
    }
}

extern "C" void kernel_launch(void* const* d_in, const int* in_sizes, int n_in,
                              void* d_out, int out_size, void* d_ws, size_t ws_size,
                              hipStream_t stream) {
    const float* X = (const float*)d_in[0];   // [64, 1024]
    const float* W = (const float*)d_in[1];   // [1025, 1024]
    float* out = (float*)d_out;               // [64, 1024]

    float* sx   = (float*)d_ws;                                        // [64, PITCH]
    int*   soff = (int*)((char*)d_ws + BATCH * PITCH * sizeof(float)); // [64, PITCH]

    dim3 g1(5, BATCH);
    rank_kernel<<<g1, 256, 0, stream>>>(X, sx, soff);

    dim3 g2(M_OUT / CPB, BATCH);
    snn_scan<<<g2, 1024, 0, stream>>>(W, sx, soff, out);
}

// Round 11
// 98.327 us; speedup vs baseline: 1.0584x; 1.0584x over previous
//
#include <hip/hip_runtime.h>
#include <math.h>

#define MAXT 100000.0f
#define M_OUT 1024
#define BATCH 64
#define PITCH 1036      // 1025 real + pads to cover depth-2 prefetch overrun
#define NSEG 16
#define SEGLEN 64

#define WALL() __builtin_amdgcn_sched_barrier(0)

// ---------------------------------------------------------------------------
// Kernel 1: stable rank via u32 keys (21 mantissa bits || 11 index bits).
// X in [1,2): bits-0x3F800000 fits 23 bits; >>2 keeps 21 (4-ulp ties fall to
// index order = adjacent-swap perturbation, compensated by the scan's window
// algebra — validated R9/R10: absmax 16). Keys unique -> rank is a perm.
// Writes TRUE x to sx, byte row offsets to soff; rewrites pads every launch
// (ws re-poisoned 0xAA).
// ---------------------------------------------------------------------------
__global__ __launch_bounds__(256) void rank_kernel(const float* __restrict__ X,
                                                   float* __restrict__ sx,
                                                   int* __restrict__ soff) {
    const int b = blockIdx.y;
    const int tid = threadIdx.x;
    __shared__ __align__(16) unsigned keys[1032];

    float myx = 1.0f;   // i == 1024 (bias) keeps this default
#pragma unroll
    for (int c = 0; c < 4; ++c) {
        const int i = c * 256 + tid;
        const float v = X[b * 1024 + i];
        keys[i] = (((__float_as_uint(v) - 0x3F800000u) >> 2) << 11) | (unsigned)i;
        if (c == blockIdx.x) myx = v;
    }
    if (tid == 0) keys[1024] = 1024u;                       // bias: mantissa 0 | idx 1024
    else if (tid < 8) keys[1024 + tid] = 0xFFFFFFFFu;       // pads: > all real keys
    __syncthreads();

    const int i = blockIdx.x * 256 + tid;
    if (i > 1024) {
        if (i < PITCH) { sx[b * PITCH + i] = MAXT; soff[b * PITCH + i] = 0; }
        return;
    }
    const unsigned ki = keys[i];
    int r0 = 0, r1 = 0;
#pragma unroll 8
    for (int j = 0; j < 1032; j += 8) {
        const uint4 a = *(const uint4*)&keys[j];
        const uint4 c = *(const uint4*)&keys[j + 4];
        r0 += (int)(a.x < ki) + (int)(a.y < ki) + (int)(a.z < ki) + (int)(a.w < ki);
        r1 += (int)(c.x < ki) + (int)(c.y < ki) + (int)(c.z < ki) + (int)(c.w < ki);
    }
    const int rank = r0 + r1;
    sx[b * PITCH + rank]   = myx;
    soff[b * PITCH + rank] = i * 4096;                      // byte offset into W
}

// ---------------------------------------------------------------------------
// Kernel 2: decoupled two-pass K-scan, R9 shape (4 cols/lane, CPB=256,
// 16 waves = 16 segments), now with explicit ping-pong prefetch in BOTH
// passes: W for iter i+1 and offsets for iter i+2 are loaded before
// computing iter i, pinned by sched_barrier walls (R9/R10 post-mortem: the
// rolled loop exposed ds_read->global_load->use every iteration, capping
// VALUBusy at ~55%).
// Step algebra (R11): windows are ordered in k, so min over valid k = FIRST
// valid -> lock via bd sign; gates cross-multiplied (no div/rcp in loop;
// dn<0 acceptance needs measure-zero float ties); cw stays an exact
// __fadd_rn chain; one IEEE div at the end, bd<=0 -> MAXT.
// ---------------------------------------------------------------------------
__global__ __launch_bounds__(1024, 4) void snn_scan(const float* __restrict__ W,
                                                    const float* __restrict__ sx,
                                                    const int* __restrict__ soff,
                                                    float* __restrict__ out) {
    const int b    = blockIdx.y;
    const int tid  = threadIdx.x;
    const int w    = tid >> 6;        // wave = K-segment id, 0..15
    const int lane = tid & 63;

    __shared__ __align__(16) float xs_s[PITCH];
    __shared__ __align__(16) int   off_s[PITCH];
    __shared__ __align__(16) float segw [NSEG][256];
    __shared__ __align__(16) float segwt[NSEG][256];
    __shared__ __align__(16) float best [NSEG][256];

    xs_s[tid]  = sx[b * PITCH + tid];
    off_s[tid] = soff[b * PITCH + tid];
    if (tid < PITCH - 1024) {
        xs_s[1024 + tid]  = sx[b * PITCH + 1024 + tid];
        off_s[1024 + tid] = soff[b * PITCH + 1024 + tid];
    }
    __syncthreads();

    const char* Wq = (const char*)W + (size_t)(blockIdx.x * 256 + lane * 4) * 4;
    const int4* off4 = (const int4*)off_s;
    const int k0 = w * SEGLEN;
    const int base = k0 >> 2;

    float cw0 = 0, cw1 = 0, cw2 = 0, cw3 = 0;
    float ct0 = 0, ct1 = 0, ct2 = 0, ct3 = 0;

#define LOAD4(o, a0, a1, a2, a3)                                               \
    a0 = *(const float4*)(Wq + (o).x); a1 = *(const float4*)(Wq + (o).y);      \
    a2 = *(const float4*)(Wq + (o).z); a3 = *(const float4*)(Wq + (o).w);

#define ACC(wv, xx)                                                            \
    cw0 = __fadd_rn(cw0, (wv).x); ct0 = __builtin_fmaf((wv).x, (xx), ct0);     \
    cw1 = __fadd_rn(cw1, (wv).y); ct1 = __builtin_fmaf((wv).y, (xx), ct1);     \
    cw2 = __fadd_rn(cw2, (wv).z); ct2 = __builtin_fmaf((wv).z, (xx), ct2);     \
    cw3 = __fadd_rn(cw3, (wv).w); ct3 = __builtin_fmaf((wv).w, (xx), ct3);

    // ---- pass 1: segment sums, prefetch-pipelined ----
    {
        int4 oc = off4[base];
        int4 on = off4[base + 1];
        float4 a0, a1, a2, a3;
        LOAD4(oc, a0, a1, a2, a3);
        for (int it = 0; it < 16; ++it) {
            WALL();
            float4 n0, n1, n2, n3;
            LOAD4(on, n0, n1, n2, n3);              // W for iter it+1
            const int4 of = off4[base + it + 2];    // offsets for iter it+2 (pads safe)
            WALL();
            const int k = k0 + it * 4;
            ACC(a0, xs_s[k]);     ACC(a1, xs_s[k + 1]);
            ACC(a2, xs_s[k + 2]); ACC(a3, xs_s[k + 3]);
            a0 = n0; a1 = n1; a2 = n2; a3 = n3; on = of;
        }
    }
    *(float4*)&segw[w][lane * 4]  = make_float4(cw0, cw1, cw2, cw3);
    *(float4*)&segwt[w][lane * 4] = make_float4(ct0, ct1, ct2, ct3);
    __syncthreads();

    // ---- exclusive prefix over segments (ascending s) ----
    cw0 = cw1 = cw2 = cw3 = ct0 = ct1 = ct2 = ct3 = 0.0f;
    for (int s = 0; s < w; ++s) {
        const float4 a = *(const float4*)&segw[s][lane * 4];
        const float4 t = *(const float4*)&segwt[s][lane * 4];
        cw0 = __fadd_rn(cw0, a.x); cw1 = __fadd_rn(cw1, a.y);
        cw2 = __fadd_rn(cw2, a.z); cw3 = __fadd_rn(cw3, a.w);
        ct0 = __fadd_rn(ct0, t.x); ct1 = __fadd_rn(ct1, t.y);
        ct2 = __fadd_rn(ct2, t.z); ct3 = __fadd_rn(ct3, t.w);
    }

    // ---- pass 2: gated scan with first-valid lock, prefetch-pipelined ----
    float bn0 = 0, bn1 = 0, bn2 = 0, bn3 = 0;
    float bd0 = -1.0f, bd1 = -1.0f, bd2 = -1.0f, bd3 = -1.0f;

#define GATE(cwv, ctv, bnv, bdv, wvv, xx, xxn)                                 \
    {                                                                          \
        cwv = __fadd_rn(cwv, (wvv));                                           \
        ctv = __builtin_fmaf((wvv), (xx), ctv);                                \
        const float dn = __fadd_rn(cwv, -1.0f);                                \
        const bool v = (ctv >= __fmul_rn((xx), dn))                            \
                     & (ctv <= __fmul_rn((xxn), dn));                          \
        const bool u = v & (bdv < 0.0f);                                       \
        bnv = u ? ctv : bnv;                                                   \
        bdv = u ? dn  : bdv;                                                   \
    }

#define GATE4(wv, xx, xxn)                                                     \
    GATE(cw0, ct0, bn0, bd0, (wv).x, (xx), (xxn))                              \
    GATE(cw1, ct1, bn1, bd1, (wv).y, (xx), (xxn))                              \
    GATE(cw2, ct2, bn2, bd2, (wv).z, (xx), (xxn))                              \
    GATE(cw3, ct3, bn3, bd3, (wv).w, (xx), (xxn))

    {
        int4 oc = off4[base];
        int4 on = off4[base + 1];
        float4 a0, a1, a2, a3;
        LOAD4(oc, a0, a1, a2, a3);
        for (int it = 0; it < 16; ++it) {
            WALL();
            float4 n0, n1, n2, n3;
            LOAD4(on, n0, n1, n2, n3);
            const int4 of = off4[base + it + 2];
            WALL();
            const int k = k0 + it * 4;
            const float xa = xs_s[k],     xb = xs_s[k + 1];
            const float xc = xs_s[k + 2], xd = xs_s[k + 3], xe = xs_s[k + 4];
            GATE4(a0, xa, xb); GATE4(a1, xb, xc);
            GATE4(a2, xc, xd); GATE4(a3, xd, xe);
            a0 = n0; a1 = n1; a2 = n2; a3 = n3; on = of;
        }
        if (w == NSEG - 1) {
            // epilogue row 1024: a0 now holds W[off_s[1024]] (loaded at it=15)
            const float xe = xs_s[1024], xen = xs_s[1025];   // xen = MAXT pad
            GATE4(a0, xe, xen);
        }
    }

    const float c0 = (bd0 > 0.0f) ? bn0 / bd0 : MAXT;   // exact IEEE div
    const float c1 = (bd1 > 0.0f) ? bn1 / bd1 : MAXT;
    const float c2 = (bd2 > 0.0f) ? bn2 / bd2 : MAXT;
    const float c3 = (bd3 > 0.0f) ? bn3 / bd3 : MAXT;
    *(float4*)&best[w][lane * 4] = make_float4(c0, c1, c2, c3);
    __syncthreads();

    // ---- cross-segment min + store ----
    if (tid < 256) {
        float r = best[0][tid];
#pragma unroll
        for (int s = 1; s < NSEG; ++s) r = fminf(r, best[s][tid]);
        out[b * M_OUT + blockIdx.x * 256 + tid] = r;
    }
}

extern "C" void kernel_launch(void* const* d_in, const int* in_sizes, int n_in,
                              void* d_out, int out_size, void* d_ws, size_t ws_size,
                              hipStream_t stream) {
    const float* X = (const float*)d_in[0];   // [64, 1024]
    const float* W = (const float*)d_in[1];   // [1025, 1024]
    float* out = (float*)d_out;               // [64, 1024]

    float* sx   = (float*)d_ws;                                        // [64, PITCH]
    int*   soff = (int*)((char*)d_ws + BATCH * PITCH * sizeof(float)); // [64, PITCH]

    dim3 g1(5, BATCH);
    rank_kernel<<<g1, 256, 0, stream>>>(X, sx, soff);

    dim3 g2(M_OUT / 256, BATCH);
    snn_scan<<<g2, 1024, 0, stream>>>(W, sx, soff, out);
}